// Round 4
// baseline (3233.829 us; speedup 1.0000x reference)
//
#include <hip/hip_runtime.h>
#include <stdint.h>

#define NPTS 32768
#define KOFF 27
#define CH   128
#define NC   (NPTS*CH)

// ---------------------------------------------------------------------------
// zero the 512-float stats area (4 per-channel vectors of 128)
// ---------------------------------------------------------------------------
__global__ void zero_stats_kernel(float* stat)
{
    stat[blockIdx.x * 256 + threadIdx.x] = 0.0f;
}

// ---------------------------------------------------------------------------
// gathered conv (VALU, fp32):
//   y[n][d] = sum_k sum_c x[nbr[n][k]][c] * W[k][c][d]
// block = 8 points x 128 channels; thread: p = tid>>5, d-group = (tid&31)*4
// ---------------------------------------------------------------------------
__global__ __launch_bounds__(256)
void ResidualBlock_77498389889548_kernel(const float* __restrict__ x,
                                         const int* __restrict__ nbr,
                                         const float* __restrict__ W,
                                         float* __restrict__ y)
{
    __shared__ float xs[8][CH];
    const int tid = threadIdx.x;
    const int p   = tid >> 5;          // point 0..7
    const int dg  = (tid & 31) * 4;    // output channel group
    const int n0  = blockIdx.x * 8;

    float a0 = 0.0f, a1 = 0.0f, a2 = 0.0f, a3 = 0.0f;

    for (int k = 0; k < KOFF; ++k) {
        int nb = nbr[(n0 + p) * KOFF + k];
        nb = ((unsigned)nb < (unsigned)NPTS) ? nb : 0;   // diagnostic clamp
        // stage gathered row p: 32 threads each load one float4 (full 128 ch)
        *(float4*)&xs[p][dg] = *(const float4*)(x + (size_t)nb * CH + dg);
        __syncthreads();

        const float* wk = W + (size_t)k * CH * CH + dg;
        for (int c = 0; c < CH; ++c) {
            const float xv = xs[p][c];
            float4 wv = *(const float4*)(wk + (size_t)c * CH);
            a0 += xv * wv.x;
            a1 += xv * wv.y;
            a2 += xv * wv.z;
            a3 += xv * wv.w;
        }
        __syncthreads();
    }

    float4 o; o.x = a0; o.y = a1; o.z = a2; o.w = a3;
    *(float4*)(y + (size_t)(n0 + p) * CH + dg) = o;
}

// ---------------------------------------------------------------------------
// per-channel sum / sumsq, block-reduce then one atomic each
// ---------------------------------------------------------------------------
__global__ __launch_bounds__(256)
void stats_kernel(const float* __restrict__ y,
                  float* __restrict__ sums, float* __restrict__ sumsq)
{
    __shared__ float r1[256], r2[256];
    const int tid = threadIdx.x;
    const int c = tid & 127, rs = tid >> 7;
    const int b = blockIdx.x;
    float s = 0.0f, s2 = 0.0f;
    for (int r = rs; r < 256; r += 2) {
        float v = y[(size_t)(b * 256 + r) * CH + c];
        s += v; s2 += v * v;
    }
    r1[tid] = s; r2[tid] = s2;
    __syncthreads();
    if (tid < 128) {
        atomicAdd(&sums[tid],  r1[tid] + r1[tid + 128]);
        atomicAdd(&sumsq[tid], r2[tid] + r2[tid + 128]);
    }
}

// ---------------------------------------------------------------------------
// in-place: y <- relu(bn(y; g,b))  (fp32)
// ---------------------------------------------------------------------------
__global__ __launch_bounds__(256)
void norm_relu_kernel(float* __restrict__ y, const float* __restrict__ sums,
                      const float* __restrict__ sumsq, const float* __restrict__ gam,
                      const float* __restrict__ bet)
{
    __shared__ float sc[128], sh[128];
    const int tid = threadIdx.x;
    if (tid < 128) {
        float mu  = sums[tid] * (1.0f / NPTS);
        float var = fmaxf(sumsq[tid] * (1.0f / NPTS) - mu * mu, 0.0f);
        float rs  = rsqrtf(var + 1e-5f);
        float s   = rs * gam[tid];
        sc[tid] = s; sh[tid] = bet[tid] - mu * s;
    }
    __syncthreads();
    size_t e = ((size_t)blockIdx.x * 256 + tid) * 4;
    int c0 = (int)(e & 127);
    float4 in = *(const float4*)(y + e);
    float4 o;
    o.x = fmaxf(in.x * sc[c0 + 0] + sh[c0 + 0], 0.0f);
    o.y = fmaxf(in.y * sc[c0 + 1] + sh[c0 + 1], 0.0f);
    o.z = fmaxf(in.z * sc[c0 + 2] + sh[c0 + 2], 0.0f);
    o.w = fmaxf(in.w * sc[c0 + 3] + sh[c0 + 3], 0.0f);
    *(float4*)(y + e) = o;
}

// ---------------------------------------------------------------------------
// out = relu(bn(y2; g,b) + feats)   (fp32); NaN -> 12345 diagnostic marker
// ---------------------------------------------------------------------------
__device__ __forceinline__ float relu_diag(float v) {
    return (v == v) ? fmaxf(v, 0.0f) : 12345.0f;
}

__global__ __launch_bounds__(256)
void final_kernel(const float* __restrict__ y, const float* __restrict__ sums,
                  const float* __restrict__ sumsq, const float* __restrict__ gam,
                  const float* __restrict__ bet, const float* __restrict__ feats,
                  float* __restrict__ out)
{
    __shared__ float sc[128], sh[128];
    const int tid = threadIdx.x;
    if (tid < 128) {
        float mu  = sums[tid] * (1.0f / NPTS);
        float var = fmaxf(sumsq[tid] * (1.0f / NPTS) - mu * mu, 0.0f);
        float rs  = rsqrtf(var + 1e-5f);
        float s   = rs * gam[tid];
        sc[tid] = s; sh[tid] = bet[tid] - mu * s;
    }
    __syncthreads();
    size_t e = ((size_t)blockIdx.x * 256 + tid) * 4;
    int c0 = (int)(e & 127);
    float4 in = *(const float4*)(y + e);
    float4 ft = *(const float4*)(feats + e);
    float4 o;
    o.x = relu_diag(in.x * sc[c0 + 0] + sh[c0 + 0] + ft.x);
    o.y = relu_diag(in.y * sc[c0 + 1] + sh[c0 + 1] + ft.y);
    o.z = relu_diag(in.z * sc[c0 + 2] + sh[c0 + 2] + ft.z);
    o.w = relu_diag(in.w * sc[c0 + 3] + sh[c0 + 3] + ft.w);
    *(float4*)(out + e) = o;
}

// ---------------------------------------------------------------------------
extern "C" void kernel_launch(void* const* d_in, const int* in_sizes, int n_in,
                              void* d_out, int out_size, void* d_ws, size_t ws_size,
                              hipStream_t stream)
{
    const float* feats = (const float*)d_in[0];
    const int*   nbr   = (const int*)d_in[1];
    const float* W1    = (const float*)d_in[2];
    const float* g1    = (const float*)d_in[3];
    const float* b1    = (const float*)d_in[4];
    const float* W2    = (const float*)d_in[5];
    const float* g2    = (const float*)d_in[6];
    const float* b2    = (const float*)d_in[7];
    float* out = (float*)d_out;

    // workspace: y2 (NC fp32 = 16 MB) + 512 stat floats
    float* y2   = (float*)d_ws;
    float* stat = y2 + (size_t)NC;

    zero_stats_kernel<<<dim3(2), 256, 0, stream>>>(stat);
    // conv1: y1 -> d_out
    ResidualBlock_77498389889548_kernel<<<dim3(NPTS / 8), 256, 0, stream>>>(feats, nbr, W1, out);
    stats_kernel<<<dim3(NPTS / 256), 256, 0, stream>>>(out, stat, stat + 128);
    // x2 = relu(bn(y1)) in-place in d_out
    norm_relu_kernel<<<dim3(NC / 1024), 256, 0, stream>>>(out, stat, stat + 128, g1, b1);
    // conv2: y2 -> ws
    ResidualBlock_77498389889548_kernel<<<dim3(NPTS / 8), 256, 0, stream>>>(out, nbr, W2, y2);
    stats_kernel<<<dim3(NPTS / 256), 256, 0, stream>>>(y2, stat + 256, stat + 384);
    final_kernel<<<dim3(NC / 1024), 256, 0, stream>>>(y2, stat + 256, stat + 384, g2, b2, feats, out);
}

// Round 5
// 270.723 us; speedup vs baseline: 11.9452x; 11.9452x over previous
//
#include <hip/hip_runtime.h>
#include <stdint.h>

#define NPTS 32768
#define KOFF 27
#define CH   128
#define NC   (NPTS*CH)
#define TILE_M 128

typedef __attribute__((ext_vector_type(8))) short short8;   // 8 bf16 (MFMA A/B frag)
typedef __attribute__((ext_vector_type(4))) float f32x4;    // MFMA C/D frag
typedef unsigned short u16;

__device__ __forceinline__ u16 f2bf(float f) {
    union { float f; uint32_t i; } v; v.f = f;
    return (u16)((v.i + 0x7FFF + ((v.i >> 16) & 1)) >> 16);  // RNE
}

// ---------------------------------------------------------------------------
// prep_w: W[k][c][d] fp32 -> Wt[k][d][c] bf16 (both convs); block 0 zeros stats
// ---------------------------------------------------------------------------
__global__ __launch_bounds__(256)
void prep_w_kernel(const float* __restrict__ W1, const float* __restrict__ W2,
                   u16* __restrict__ W1t, u16* __restrict__ W2t,
                   float* __restrict__ stat)
{
    __shared__ u16 t[128*129];
    const int b = blockIdx.x, tid = threadIdx.x;
    if (b == 0) for (int i = tid; i < 512; i += 256) stat[i] = 0.0f;
    const float* src = (b < KOFF) ? W1 + (size_t)b*CH*CH : W2 + (size_t)(b-KOFF)*CH*CH;
    u16* dst         = (b < KOFF) ? W1t + (size_t)b*CH*CH : W2t + (size_t)(b-KOFF)*CH*CH;
    for (int e = tid; e < CH*CH; e += 256) {
        int c = e >> 7, d = e & 127;
        t[d*129 + c] = f2bf(src[e]);
    }
    __syncthreads();
    for (int e = tid; e < CH*CH; e += 256) {
        int d = e >> 7, c = e & 127;
        dst[e] = t[d*129 + c];
    }
}

// ---------------------------------------------------------------------------
// cvt: fp32 -> bf16, 8 elements/thread
// ---------------------------------------------------------------------------
__global__ __launch_bounds__(256)
void cvt_kernel(const float* __restrict__ x, u16* __restrict__ xb)
{
    size_t e = ((size_t)blockIdx.x * 256 + threadIdx.x) * 8;
    float4 a = *(const float4*)(x + e);
    float4 b = *(const float4*)(x + e + 4);
    ushort4 lo, hi;
    lo.x = f2bf(a.x); lo.y = f2bf(a.y); lo.z = f2bf(a.z); lo.w = f2bf(a.w);
    hi.x = f2bf(b.x); hi.y = f2bf(b.y); hi.z = f2bf(b.z); hi.w = f2bf(b.w);
    *(ushort4*)(xb + e) = lo;
    *(ushort4*)(xb + e + 4) = hi;
}

// ---------------------------------------------------------------------------
// gathered MFMA GEMM. Grid (M-tiles, ksplit). part buffer selected by kg.
// 128x128 tile, 4 waves (64x64 each), 16x16x32 bf16 MFMA, BK=64,
// XOR-swizzled LDS staging via 16B register loads + ds_write_b128.
// ---------------------------------------------------------------------------
__global__ __launch_bounds__(256)
void ResidualBlock_77498389889548_kernel(const u16* __restrict__ xb,
                                         const int* __restrict__ nbr,
                                         const u16* __restrict__ Wt,
                                         float* __restrict__ part0,
                                         float* __restrict__ part1,
                                         float* __restrict__ part2,
                                         int kpg)
{
    __shared__ __align__(16) u16 A_lds[TILE_M*64];   // 16 KB swizzled
    __shared__ __align__(16) u16 B_lds[CH*64];       // 16 KB swizzled
    __shared__ int idx_lds[TILE_M*KOFF];             // [kk][row], 13.8 KB max

    const int tid = threadIdx.x;
    const int n0  = blockIdx.x * TILE_M;
    const int kg  = blockIdx.y;

    for (int e = tid; e < TILE_M*kpg; e += 256) {
        int kk = e >> 7, nl = e & 127;
        int nb = nbr[(size_t)(n0 + nl)*KOFF + kg*kpg + kk];
        idx_lds[e] = ((unsigned)nb < (unsigned)NPTS) ? nb : 0;
    }
    __syncthreads();

    const int wave = tid >> 6;
    const int lane = tid & 63;
    const int wrow = (wave >> 1) * 64;
    const int wcol = (wave & 1) * 64;
    const int lm   = lane & 15;
    const int quad = lane >> 4;
    const int srow = tid >> 3;    // staging row 0..31 (plus j*32)
    const int sci  = tid & 7;     // staging 16B chunk 0..7

    f32x4 acc[4][4];
    #pragma unroll
    for (int i = 0; i < 4; ++i)
        #pragma unroll
        for (int j = 0; j < 4; ++j)
            #pragma unroll
            for (int r = 0; r < 4; ++r) acc[i][j][r] = 0.0f;

    int aoff[2][4], boff[2][4];
    #pragma unroll
    for (int kc = 0; kc < 2; ++kc) {
        int g = kc*4 + quad;
        #pragma unroll
        for (int i = 0; i < 4; ++i) {
            int row = wrow + i*16 + lm;
            aoff[kc][i] = row*128 + ((g ^ (row & 7)) << 4);
            int d = wcol + i*16 + lm;
            boff[kc][i] = d*128 + ((g ^ (d & 7)) << 4);
        }
    }

    char* Ab = (char*)A_lds;
    char* Bb = (char*)B_lds;

    for (int it = 0; it < kpg*2; ++it) {
        const int kk = it >> 1;
        const int h  = it & 1;
        const int kglob = kg*kpg + kk;
        const u16* wbase = Wt + (size_t)kglob*CH*CH + h*64 + sci*8;

        short8 av[4], bv[4];
        #pragma unroll
        for (int j = 0; j < 4; ++j) {
            int row = j*32 + srow;
            int nb  = idx_lds[kk*128 + row];
            av[j] = *(const short8*)(xb + (size_t)nb*CH + h*64 + sci*8);
            bv[j] = *(const short8*)(wbase + (size_t)row*CH);
        }
        #pragma unroll
        for (int j = 0; j < 4; ++j) {
            int row = j*32 + srow;
            int slot = (sci ^ (row & 7)) << 4;
            *(short8*)(Ab + row*128 + slot) = av[j];
            *(short8*)(Bb + row*128 + slot) = bv[j];
        }
        __syncthreads();

        #pragma unroll
        for (int kc = 0; kc < 2; ++kc) {
            short8 a[4], b[4];
            #pragma unroll
            for (int i = 0; i < 4; ++i) a[i] = *(const short8*)(Ab + aoff[kc][i]);
            #pragma unroll
            for (int j = 0; j < 4; ++j) b[j] = *(const short8*)(Bb + boff[kc][j]);
            #pragma unroll
            for (int i = 0; i < 4; ++i)
                #pragma unroll
                for (int j = 0; j < 4; ++j)
                    acc[i][j] = __builtin_amdgcn_mfma_f32_16x16x32_bf16(a[i], b[j], acc[i][j], 0, 0, 0);
        }
        __syncthreads();
    }

    float* pb = (kg == 0) ? part0 : ((kg == 1) ? part1 : part2);
    const int colb = wcol + lm;
    #pragma unroll
    for (int i = 0; i < 4; ++i) {
        int row0 = n0 + wrow + i*16 + quad*4;
        #pragma unroll
        for (int r = 0; r < 4; ++r) {
            float* rp = pb + (size_t)(row0 + r)*CH + colb;
            #pragma unroll
            for (int j = 0; j < 4; ++j) rp[j*16] = acc[i][j][r];
        }
    }
}

// ---------------------------------------------------------------------------
// stats: y = sum of npart partials -> p0 in place; per-channel sum/sumsq
// ---------------------------------------------------------------------------
__global__ __launch_bounds__(256)
void stats_kernel(float* __restrict__ p0, const float* __restrict__ p1,
                  const float* __restrict__ p2, int npart,
                  float* __restrict__ sums, float* __restrict__ sumsq)
{
    __shared__ float r1[256], r2[256];
    const int tid = threadIdx.x;
    const int c = tid & 127, rs = tid >> 7;
    const int b = blockIdx.x;
    float s = 0.0f, s2 = 0.0f;
    for (int r = rs; r < 128; r += 2) {
        size_t e = (size_t)(b*128 + r)*CH + c;
        float v = p0[e];
        if (npart == 3) { v += p1[e] + p2[e]; p0[e] = v; }
        s += v; s2 += v*v;
    }
    r1[tid] = s; r2[tid] = s2;
    __syncthreads();
    if (tid < 128) {
        atomicAdd(&sums[tid],  r1[tid] + r1[tid+128]);
        atomicAdd(&sumsq[tid], r2[tid] + r2[tid+128]);
    }
}

// ---------------------------------------------------------------------------
// norm_relu: xo(bf16) = relu(bn(y; g,b)),  y fp32
// ---------------------------------------------------------------------------
__global__ __launch_bounds__(256)
void norm_relu_kernel(const float* __restrict__ y, const float* __restrict__ sums,
                      const float* __restrict__ sumsq, const float* __restrict__ gam,
                      const float* __restrict__ bet, u16* __restrict__ xo)
{
    __shared__ float sc[128], sh[128];
    const int tid = threadIdx.x;
    if (tid < 128) {
        float mu  = sums[tid] * (1.0f/NPTS);
        float var = fmaxf(sumsq[tid] * (1.0f/NPTS) - mu*mu, 0.0f);
        float rs  = rsqrtf(var + 1e-5f);
        float s   = rs * gam[tid];
        sc[tid] = s; sh[tid] = bet[tid] - mu*s;
    }
    __syncthreads();
    size_t e = ((size_t)blockIdx.x*256 + tid) * 4;
    int c0 = (int)(e & 127);
    float4 in = *(const float4*)(y + e);
    ushort4 o;
    o.x = f2bf(fmaxf(in.x*sc[c0+0] + sh[c0+0], 0.0f));
    o.y = f2bf(fmaxf(in.y*sc[c0+1] + sh[c0+1], 0.0f));
    o.z = f2bf(fmaxf(in.z*sc[c0+2] + sh[c0+2], 0.0f));
    o.w = f2bf(fmaxf(in.w*sc[c0+3] + sh[c0+3], 0.0f));
    *(ushort4*)(xo + e) = o;
}

// ---------------------------------------------------------------------------
// final: out = relu(bn(y2; g,b) + feats)  (fp32; out may alias y)
// ---------------------------------------------------------------------------
__global__ __launch_bounds__(256)
void final_kernel(const float* __restrict__ y, const float* __restrict__ sums,
                  const float* __restrict__ sumsq, const float* __restrict__ gam,
                  const float* __restrict__ bet, const float* __restrict__ feats,
                  float* __restrict__ out)
{
    __shared__ float sc[128], sh[128];
    const int tid = threadIdx.x;
    if (tid < 128) {
        float mu  = sums[tid] * (1.0f/NPTS);
        float var = fmaxf(sumsq[tid] * (1.0f/NPTS) - mu*mu, 0.0f);
        float rs  = rsqrtf(var + 1e-5f);
        float s   = rs * gam[tid];
        sc[tid] = s; sh[tid] = bet[tid] - mu*s;
    }
    __syncthreads();
    size_t e = ((size_t)blockIdx.x*256 + tid) * 4;
    int c0 = (int)(e & 127);
    float4 in = *(const float4*)(y + e);
    float4 ft = *(const float4*)(feats + e);
    float4 o;
    o.x = fmaxf(in.x*sc[c0+0] + sh[c0+0] + ft.x, 0.0f);
    o.y = fmaxf(in.y*sc[c0+1] + sh[c0+1] + ft.y, 0.0f);
    o.z = fmaxf(in.z*sc[c0+2] + sh[c0+2] + ft.z, 0.0f);
    o.w = fmaxf(in.w*sc[c0+3] + sh[c0+3] + ft.w, 0.0f);
    *(float4*)(out + e) = o;
}

// ---------------------------------------------------------------------------
extern "C" void kernel_launch(void* const* d_in, const int* in_sizes, int n_in,
                              void* d_out, int out_size, void* d_ws, size_t ws_size,
                              hipStream_t stream)
{
    const float* feats = (const float*)d_in[0];
    const int*   nbr   = (const int*)d_in[1];
    const float* W1    = (const float*)d_in[2];
    const float* g1    = (const float*)d_in[3];
    const float* b1    = (const float*)d_in[4];
    const float* W2    = (const float*)d_in[5];
    const float* g2    = (const float*)d_in[6];
    const float* b2    = (const float*)d_in[7];
    float* out = (float*)d_out;

    // ws: xbuf bf16 (feats_bf16, later x2_bf16) | Wt1 | Wt2 | stat | [part1 part2]
    char* ws = (char*)d_ws;
    u16*   xbuf = (u16*)ws;                                   // 8.4 MB
    u16*   W1t  = xbuf + (size_t)NC;
    u16*   W2t  = W1t + (size_t)KOFF*CH*CH;
    float* stat = (float*)(W2t + (size_t)KOFF*CH*CH);
    float* part1 = stat + 512;                                // NC*4 each (tier 3 only)
    float* part2 = part1 + (size_t)NC;
    float* part0 = out;                                       // aliases d_out

    size_t need3 = (size_t)((char*)(part2 + (size_t)NC) - ws);
    const int ksplit = (ws_size >= need3) ? 3 : 1;
    const int kpg = KOFF / ksplit;

    prep_w_kernel<<<dim3(2*KOFF), 256, 0, stream>>>(W1, W2, W1t, W2t, stat);
    cvt_kernel<<<dim3(NC/2048), 256, 0, stream>>>(feats, xbuf);

    ResidualBlock_77498389889548_kernel<<<dim3(NPTS/TILE_M, ksplit), 256, 0, stream>>>(
        xbuf, nbr, W1t, part0, part1, part2, kpg);
    stats_kernel<<<dim3(NPTS/128), 256, 0, stream>>>(part0, part1, part2, ksplit, stat, stat + 128);
    norm_relu_kernel<<<dim3(NC/1024), 256, 0, stream>>>(part0, stat, stat + 128, g1, b1, xbuf);

    ResidualBlock_77498389889548_kernel<<<dim3(NPTS/TILE_M, ksplit), 256, 0, stream>>>(
        xbuf, nbr, W2t, part0, part1, part2, kpg);
    stats_kernel<<<dim3(NPTS/128), 256, 0, stream>>>(part0, part1, part2, ksplit, stat + 256, stat + 384);
    final_kernel<<<dim3(NC/1024), 256, 0, stream>>>(part0, stat + 256, stat + 384, g2, b2, feats, out);
}

// Round 6
// 260.092 us; speedup vs baseline: 12.4334x; 1.0409x over previous
//
#include <hip/hip_runtime.h>
#include <stdint.h>

#define NPTS 32768
#define KOFF 27
#define CH   128
#define NC   (NPTS*CH)
#define KSPLIT 3
#define KPG  9
#define TILE_M 128

typedef __attribute__((ext_vector_type(8))) short short8;   // 8 bf16 (MFMA A/B frag)
typedef __attribute__((ext_vector_type(4))) float f32x4;    // MFMA C/D frag
typedef unsigned short u16;

__device__ __forceinline__ u16 f2bf(float f) {
    union { float f; uint32_t i; } v; v.f = f;
    return (u16)((v.i + 0x7FFF + ((v.i >> 16) & 1)) >> 16);  // RNE
}

#define GLDS16(gp, lp) __builtin_amdgcn_global_load_lds( \
    (__attribute__((address_space(1))) void*)(gp),           \
    (__attribute__((address_space(3))) void*)(lp), 16, 0, 0)

// ---------------------------------------------------------------------------
// prep (fused): b<54 -> W[k][c][d] fp32 -> Wt[k][d][c] bf16; block 0 zeros
// stats; b>=54 -> feats fp32 -> bf16 (8 elems/thread)
// ---------------------------------------------------------------------------
__global__ __launch_bounds__(256)
void prep_kernel(const float* __restrict__ W1, const float* __restrict__ W2,
                 u16* __restrict__ W1t, u16* __restrict__ W2t,
                 const float* __restrict__ feats, u16* __restrict__ xbuf,
                 float* __restrict__ stat)
{
    __shared__ u16 t[128*129];
    const int b = blockIdx.x, tid = threadIdx.x;
    if (b < 2*KOFF) {
        if (b == 0) for (int i = tid; i < 512; i += 256) stat[i] = 0.0f;
        const float* src = (b < KOFF) ? W1 + (size_t)b*CH*CH : W2 + (size_t)(b-KOFF)*CH*CH;
        u16* dst         = (b < KOFF) ? W1t + (size_t)b*CH*CH : W2t + (size_t)(b-KOFF)*CH*CH;
        for (int e = tid; e < CH*CH; e += 256) {
            int c = e >> 7, d = e & 127;
            t[d*129 + c] = f2bf(src[e]);
        }
        __syncthreads();
        for (int e = tid; e < CH*CH; e += 256) {
            int d = e >> 7, c = e & 127;
            dst[e] = t[d*129 + c];
        }
    } else {
        size_t e = ((size_t)(b - 2*KOFF) * 256 + tid) * 8;
        float4 a = *(const float4*)(feats + e);
        float4 c = *(const float4*)(feats + e + 4);
        ushort4 lo, hi;
        lo.x = f2bf(a.x); lo.y = f2bf(a.y); lo.z = f2bf(a.z); lo.w = f2bf(a.w);
        hi.x = f2bf(c.x); hi.y = f2bf(c.y); hi.z = f2bf(c.z); hi.w = f2bf(c.w);
        *(ushort4*)(xbuf + e) = lo;
        *(ushort4*)(xbuf + e + 4) = hi;
    }
}

// ---------------------------------------------------------------------------
// gathered MFMA GEMM. Grid (256 M-tiles, 3 k-groups). 128x128 tile, 4 waves
// (64x64 each), 16x16x32 bf16 MFMA, BK=64, global_load_lds width-16 staging
// with source-chunk XOR swizzle (conflict-free ds_read_b128 in compute).
// ---------------------------------------------------------------------------
__global__ __launch_bounds__(256)
void ResidualBlock_77498389889548_kernel(const u16* __restrict__ xb,
                                         const int* __restrict__ nbr,
                                         const u16* __restrict__ Wt,
                                         float* __restrict__ part0,
                                         float* __restrict__ part1,
                                         float* __restrict__ part2)
{
    __shared__ __align__(16) u16 A_lds[TILE_M*64];   // 16 KB swizzled
    __shared__ __align__(16) u16 B_lds[CH*64];       // 16 KB swizzled
    __shared__ int idx_lds[KPG*TILE_M];              // 4.6 KB

    const int tid = threadIdx.x;
    const int n0  = blockIdx.x * TILE_M;
    const int kg  = blockIdx.y;

    for (int e = tid; e < TILE_M*KPG; e += 256) {
        int kk = e >> 7, nl = e & 127;
        int nb = nbr[(size_t)(n0 + nl)*KOFF + kg*KPG + kk];
        idx_lds[e] = ((unsigned)nb < (unsigned)NPTS) ? nb : 0;
    }
    __syncthreads();

    const int wave = tid >> 6;
    const int lane = tid & 63;
    const int wrow = (wave >> 1) * 64;
    const int wcol = (wave & 1) * 64;
    const int lm   = lane & 15;
    const int quad = lane >> 4;
    const int l8r  = lane >> 3;                        // row-in-8 for staging
    const int swz  = ((lane & 7) ^ l8r) << 3;          // source chunk (elements)

    f32x4 acc[4][4];
    #pragma unroll
    for (int i = 0; i < 4; ++i)
        #pragma unroll
        for (int j = 0; j < 4; ++j)
            #pragma unroll
            for (int r = 0; r < 4; ++r) acc[i][j][r] = 0.0f;

    // loop-invariant swizzled ds_read byte offsets
    int aoff[2][4], boff[2][4];
    #pragma unroll
    for (int kc = 0; kc < 2; ++kc) {
        int g = kc*4 + quad;
        #pragma unroll
        for (int i = 0; i < 4; ++i) {
            int row = wrow + i*16 + lm;
            aoff[kc][i] = row*128 + ((g ^ (row & 7)) << 4);
            int d = wcol + i*16 + lm;
            boff[kc][i] = d*128 + ((g ^ (d & 7)) << 4);
        }
    }

    const char* Ab = (const char*)A_lds;
    const char* Bb = (const char*)B_lds;

    for (int it = 0; it < KPG*2; ++it) {
        const int kk = it >> 1;
        const int h  = it & 1;
        const u16* wb = Wt + (size_t)(kg*KPG + kk)*CH*CH + h*64 + swz;

        // stage A (gather) + B via direct-to-LDS DMA: 8 rows / instruction
        #pragma unroll
        for (int j = 0; j < 4; ++j) {
            int row8 = wave*32 + j*8;                  // wave-uniform
            int nb = idx_lds[kk*128 + row8 + l8r];
            GLDS16(xb + (size_t)nb*CH + h*64 + swz, &A_lds[row8*64]);
        }
        #pragma unroll
        for (int j = 0; j < 4; ++j) {
            int row8 = wave*32 + j*8;
            GLDS16(wb + (size_t)(row8 + l8r)*CH, &B_lds[row8*64]);
        }
        __syncthreads();   // compiler drains vmcnt before barrier

        #pragma unroll
        for (int kc = 0; kc < 2; ++kc) {
            short8 a[4], b[4];
            #pragma unroll
            for (int i = 0; i < 4; ++i) a[i] = *(const short8*)(Ab + aoff[kc][i]);
            #pragma unroll
            for (int j = 0; j < 4; ++j) b[j] = *(const short8*)(Bb + boff[kc][j]);
            #pragma unroll
            for (int i = 0; i < 4; ++i)
                #pragma unroll
                for (int j = 0; j < 4; ++j)
                    acc[i][j] = __builtin_amdgcn_mfma_f32_16x16x32_bf16(a[i], b[j], acc[i][j], 0, 0, 0);
        }
        __syncthreads();   // all reads done before next overwrite
    }

    // epilogue: C/D layout col=lane&15, row=quad*4+reg
    float* pb = (kg == 0) ? part0 : ((kg == 1) ? part1 : part2);
    const int colb = wcol + lm;
    #pragma unroll
    for (int i = 0; i < 4; ++i) {
        int row0 = n0 + wrow + i*16 + quad*4;
        #pragma unroll
        for (int r = 0; r < 4; ++r) {
            float* rp = pb + (size_t)(row0 + r)*CH + colb;
            #pragma unroll
            for (int j = 0; j < 4; ++j) rp[j*16] = acc[i][j][r];
        }
    }
}

// ---------------------------------------------------------------------------
// stats: y = p0+p1+p2 -> p0 in place; per-channel sum/sumsq via atomics
// ---------------------------------------------------------------------------
__global__ __launch_bounds__(256)
void stats_kernel(float* __restrict__ p0, const float* __restrict__ p1,
                  const float* __restrict__ p2,
                  float* __restrict__ sums, float* __restrict__ sumsq)
{
    __shared__ float r1[256], r2[256];
    const int tid = threadIdx.x;
    const int c = tid & 127, rs = tid >> 7;
    const int b = blockIdx.x;
    float s = 0.0f, s2 = 0.0f;
    for (int r = rs; r < 128; r += 2) {
        size_t e = (size_t)(b*128 + r)*CH + c;
        float v = p0[e] + p1[e] + p2[e];
        p0[e] = v;
        s += v; s2 += v*v;
    }
    r1[tid] = s; r2[tid] = s2;
    __syncthreads();
    if (tid < 128) {
        atomicAdd(&sums[tid],  r1[tid] + r1[tid+128]);
        atomicAdd(&sumsq[tid], r2[tid] + r2[tid+128]);
    }
}

// ---------------------------------------------------------------------------
// norm_relu: xo(bf16) = relu(bn(y; g,b)),  y fp32
// ---------------------------------------------------------------------------
__global__ __launch_bounds__(256)
void norm_relu_kernel(const float* __restrict__ y, const float* __restrict__ sums,
                      const float* __restrict__ sumsq, const float* __restrict__ gam,
                      const float* __restrict__ bet, u16* __restrict__ xo)
{
    __shared__ float sc[128], sh[128];
    const int tid = threadIdx.x;
    if (tid < 128) {
        float mu  = sums[tid] * (1.0f/NPTS);
        float var = fmaxf(sumsq[tid] * (1.0f/NPTS) - mu*mu, 0.0f);
        float rs  = rsqrtf(var + 1e-5f);
        float s   = rs * gam[tid];
        sc[tid] = s; sh[tid] = bet[tid] - mu*s;
    }
    __syncthreads();
    size_t e = ((size_t)blockIdx.x*256 + tid) * 4;
    int c0 = (int)(e & 127);
    float4 in = *(const float4*)(y + e);
    ushort4 o;
    o.x = f2bf(fmaxf(in.x*sc[c0+0] + sh[c0+0], 0.0f));
    o.y = f2bf(fmaxf(in.y*sc[c0+1] + sh[c0+1], 0.0f));
    o.z = f2bf(fmaxf(in.z*sc[c0+2] + sh[c0+2], 0.0f));
    o.w = f2bf(fmaxf(in.w*sc[c0+3] + sh[c0+3], 0.0f));
    *(ushort4*)(xo + e) = o;
}

// ---------------------------------------------------------------------------
// final: out = relu(bn(y2; g,b) + feats)  (fp32; out aliases y)
// ---------------------------------------------------------------------------
__global__ __launch_bounds__(256)
void final_kernel(const float* __restrict__ y, const float* __restrict__ sums,
                  const float* __restrict__ sumsq, const float* __restrict__ gam,
                  const float* __restrict__ bet, const float* __restrict__ feats,
                  float* __restrict__ out)
{
    __shared__ float sc[128], sh[128];
    const int tid = threadIdx.x;
    if (tid < 128) {
        float mu  = sums[tid] * (1.0f/NPTS);
        float var = fmaxf(sumsq[tid] * (1.0f/NPTS) - mu*mu, 0.0f);
        float rs  = rsqrtf(var + 1e-5f);
        float s   = rs * gam[tid];
        sc[tid] = s; sh[tid] = bet[tid] - mu*s;
    }
    __syncthreads();
    size_t e = ((size_t)blockIdx.x*256 + tid) * 4;
    int c0 = (int)(e & 127);
    float4 in = *(const float4*)(y + e);
    float4 ft = *(const float4*)(feats + e);
    float4 o;
    o.x = fmaxf(in.x*sc[c0+0] + sh[c0+0] + ft.x, 0.0f);
    o.y = fmaxf(in.y*sc[c0+1] + sh[c0+1] + ft.y, 0.0f);
    o.z = fmaxf(in.z*sc[c0+2] + sh[c0+2] + ft.z, 0.0f);
    o.w = fmaxf(in.w*sc[c0+3] + sh[c0+3] + ft.w, 0.0f);
    *(float4*)(out + e) = o;
}

// ---------------------------------------------------------------------------
extern "C" void kernel_launch(void* const* d_in, const int* in_sizes, int n_in,
                              void* d_out, int out_size, void* d_ws, size_t ws_size,
                              hipStream_t stream)
{
    const float* feats = (const float*)d_in[0];
    const int*   nbr   = (const int*)d_in[1];
    const float* W1    = (const float*)d_in[2];
    const float* g1    = (const float*)d_in[3];
    const float* b1    = (const float*)d_in[4];
    const float* W2    = (const float*)d_in[5];
    const float* g2    = (const float*)d_in[6];
    const float* b2    = (const float*)d_in[7];
    float* out = (float*)d_out;

    // ws: xbuf bf16 (feats_bf16, later x2_bf16) | Wt1 | Wt2 | stat | part1 part2
    // (~51 MB; ws_size >= 51 MB confirmed by round-5 WRITE_SIZE = 3 partials)
    char* ws = (char*)d_ws;
    u16*   xbuf = (u16*)ws;                                   // 8.4 MB
    u16*   W1t  = xbuf + (size_t)NC;
    u16*   W2t  = W1t + (size_t)KOFF*CH*CH;
    float* stat = (float*)(W2t + (size_t)KOFF*CH*CH);
    float* part1 = stat + 512;                                // 16.8 MB
    float* part2 = part1 + (size_t)NC;                        // 16.8 MB
    float* part0 = out;                                       // aliases d_out

    prep_kernel<<<dim3(2*KOFF + NC/2048), 256, 0, stream>>>(W1, W2, W1t, W2t, feats, xbuf, stat);

    ResidualBlock_77498389889548_kernel<<<dim3(NPTS/TILE_M, KSPLIT), 256, 0, stream>>>(
        xbuf, nbr, W1t, part0, part1, part2);
    stats_kernel<<<dim3(NPTS/128), 256, 0, stream>>>(part0, part1, part2, stat, stat + 128);
    norm_relu_kernel<<<dim3(NC/1024), 256, 0, stream>>>(part0, stat, stat + 128, g1, b1, xbuf);

    ResidualBlock_77498389889548_kernel<<<dim3(NPTS/TILE_M, KSPLIT), 256, 0, stream>>>(
        xbuf, nbr, W2t, part0, part1, part2);
    stats_kernel<<<dim3(NPTS/128), 256, 0, stream>>>(part0, part1, part2, stat + 256, stat + 384);
    final_kernel<<<dim3(NC/1024), 256, 0, stream>>>(part0, stat + 256, stat + 384, g2, b2, feats, out);
}

// Round 7
// 232.528 us; speedup vs baseline: 13.9073x; 1.1185x over previous
//
#include <hip/hip_runtime.h>
#include <stdint.h>

#define NPTS 32768
#define KOFF 27
#define CH   128
#define NC   (NPTS*CH)
#define TILE_M 64
#define NITER (KOFF*2)     // 54 half-row (BK=64) steps

typedef __attribute__((ext_vector_type(8))) short short8;   // 8 bf16 (MFMA A/B frag)
typedef __attribute__((ext_vector_type(4))) float f32x4;    // MFMA C/D frag
typedef unsigned short u16;

__device__ __forceinline__ float bf2f(u16 u) {
    union { uint32_t i; float f; } v; v.i = ((uint32_t)u) << 16; return v.f;
}
__device__ __forceinline__ u16 f2bf(float f) {
    union { float f; uint32_t i; } v; v.f = f;
    return (u16)((v.i + 0x7FFF + ((v.i >> 16) & 1)) >> 16);  // RNE
}

#define GLDS16(gp, lp) __builtin_amdgcn_global_load_lds( \
    (__attribute__((address_space(1))) void*)(gp),           \
    (__attribute__((address_space(3))) void*)(lp), 16, 0, 0)

// ---------------------------------------------------------------------------
// prep (fused): b<54 -> W[k][c][d] fp32 -> Wt[k][d][c] bf16; block 0 zeros
// stats; b>=54 -> feats fp32 -> bf16 (8 elems/thread)
// ---------------------------------------------------------------------------
__global__ __launch_bounds__(256)
void prep_kernel(const float* __restrict__ W1, const float* __restrict__ W2,
                 u16* __restrict__ W1t, u16* __restrict__ W2t,
                 const float* __restrict__ feats, u16* __restrict__ xbuf,
                 float* __restrict__ stat)
{
    __shared__ u16 t[128*129];
    const int b = blockIdx.x, tid = threadIdx.x;
    if (b < 2*KOFF) {
        if (b == 0) for (int i = tid; i < 512; i += 256) stat[i] = 0.0f;
        const float* src = (b < KOFF) ? W1 + (size_t)b*CH*CH : W2 + (size_t)(b-KOFF)*CH*CH;
        u16* dst         = (b < KOFF) ? W1t + (size_t)b*CH*CH : W2t + (size_t)(b-KOFF)*CH*CH;
        for (int e = tid; e < CH*CH; e += 256) {
            int c = e >> 7, d = e & 127;
            t[d*129 + c] = f2bf(src[e]);
        }
        __syncthreads();
        for (int e = tid; e < CH*CH; e += 256) {
            int d = e >> 7, c = e & 127;
            dst[e] = t[d*129 + c];
        }
    } else {
        size_t e = ((size_t)(b - 2*KOFF) * 256 + tid) * 8;
        float4 a = *(const float4*)(feats + e);
        float4 c = *(const float4*)(feats + e + 4);
        ushort4 lo, hi;
        lo.x = f2bf(a.x); lo.y = f2bf(a.y); lo.z = f2bf(a.z); lo.w = f2bf(a.w);
        hi.x = f2bf(c.x); hi.y = f2bf(c.y); hi.z = f2bf(c.z); hi.w = f2bf(c.w);
        *(ushort4*)(xbuf + e) = lo;
        *(ushort4*)(xbuf + e + 4) = hi;
    }
}

// ---------------------------------------------------------------------------
// gathered MFMA GEMM, full K=27 per block (no partials). Grid 512 blocks,
// 64x128 tile, 4 waves each 32x64, 16x16x32 bf16 MFMA, BK=64.
// Double-buffered LDS, one barrier/iter: stage(it+1) overlaps compute(it).
// Epilogue: y bf16 + exact per-channel sum/sumsq from fp32 acc (LDS+atomics).
// ---------------------------------------------------------------------------
__global__ __launch_bounds__(256)
void ResidualBlock_77498389889548_kernel(const u16* __restrict__ xb,
                                         const int* __restrict__ nbr,
                                         const u16* __restrict__ Wt,
                                         u16* __restrict__ y,
                                         float* __restrict__ gsum,
                                         float* __restrict__ gsq)
{
    __shared__ __align__(16) u16 A_lds[2][TILE_M*64];  // 2 x 8 KB, swizzled
    __shared__ __align__(16) u16 B_lds[2][CH*64];      // 2 x 16 KB, swizzled
    __shared__ int idx_lds[KOFF*TILE_M];               // [kk][row], 6.9 KB
    __shared__ float ls[CH], lq[CH];                   // block stats

    const int tid = threadIdx.x;
    const int n0  = blockIdx.x * TILE_M;

    if (tid < CH) { ls[tid] = 0.0f; lq[tid] = 0.0f; }
    for (int e = tid; e < KOFF*TILE_M; e += 256) {
        int kk = e >> 6, r = e & 63;
        int nb = nbr[(size_t)(n0 + r)*KOFF + kk];
        idx_lds[e] = ((unsigned)nb < (unsigned)NPTS) ? nb : 0;
    }
    __syncthreads();

    const int wave = tid >> 6;
    const int lane = tid & 63;
    const int wrow = (wave >> 1) * 32;
    const int wcol = (wave & 1) * 64;
    const int lm   = lane & 15;
    const int quad = lane >> 4;
    const int l8r  = lane >> 3;                        // row-in-8 for staging
    const int swz  = ((lane & 7) ^ l8r) << 3;          // source chunk (elements)

    f32x4 acc[2][4];
    #pragma unroll
    for (int i = 0; i < 2; ++i)
        #pragma unroll
        for (int j = 0; j < 4; ++j)
            #pragma unroll
            for (int r = 0; r < 4; ++r) acc[i][j][r] = 0.0f;

    // loop-invariant swizzled ds_read byte offsets
    int aoff[2][2], boff[2][4];
    #pragma unroll
    for (int kc = 0; kc < 2; ++kc) {
        int g = kc*4 + quad;
        #pragma unroll
        for (int i = 0; i < 2; ++i) {
            int row = wrow + i*16 + lm;
            aoff[kc][i] = row*128 + ((g ^ (row & 7)) << 4);
        }
        #pragma unroll
        for (int j = 0; j < 4; ++j) {
            int d = wcol + j*16 + lm;
            boff[kc][j] = d*128 + ((g ^ (d & 7)) << 4);
        }
    }

    auto stage = [&](int it, int b) {
        const int kk = it >> 1;
        const int h  = it & 1;
        // A: 64 rows, 8 rows/instr, 2 instr/wave (gathered)
        #pragma unroll
        for (int j = 0; j < 2; ++j) {
            int row8 = wave*16 + j*8;                  // wave-uniform
            int nb = idx_lds[kk*64 + row8 + l8r];
            GLDS16(xb + (size_t)nb*CH + h*64 + swz, &A_lds[b][row8*64]);
        }
        // B: 128 rows, 4 instr/wave
        const u16* wb = Wt + (size_t)kk*CH*CH + h*64 + swz;
        #pragma unroll
        for (int j = 0; j < 4; ++j) {
            int row8 = wave*32 + j*8;
            GLDS16(wb + (size_t)(row8 + l8r)*CH, &B_lds[b][row8*64]);
        }
    };

    stage(0, 0);
    __syncthreads();

    for (int it = 0; it < NITER; ++it) {
        const int cur = it & 1;
        if (it + 1 < NITER) stage(it + 1, cur ^ 1);

        const char* Ab = (const char*)A_lds[cur];
        const char* Bb = (const char*)B_lds[cur];
        #pragma unroll
        for (int kc = 0; kc < 2; ++kc) {
            short8 a[2], b[4];
            #pragma unroll
            for (int i = 0; i < 2; ++i) a[i] = *(const short8*)(Ab + aoff[kc][i]);
            #pragma unroll
            for (int j = 0; j < 4; ++j) b[j] = *(const short8*)(Bb + boff[kc][j]);
            #pragma unroll
            for (int i = 0; i < 2; ++i)
                #pragma unroll
                for (int j = 0; j < 4; ++j)
                    acc[i][j] = __builtin_amdgcn_mfma_f32_16x16x32_bf16(a[i], b[j], acc[i][j], 0, 0, 0);
        }
        __syncthreads();   // drains next-iter loads + all cur reads
    }

    // epilogue: C/D layout col=lane&15, row=quad*4+reg
    const int colb = wcol + lm;
    #pragma unroll
    for (int i = 0; i < 2; ++i) {
        #pragma unroll
        for (int r = 0; r < 4; ++r) {
            int row = n0 + wrow + i*16 + quad*4 + r;
            u16* yp = y + (size_t)row*CH + colb;
            #pragma unroll
            for (int j = 0; j < 4; ++j) yp[j*16] = f2bf(acc[i][j][r]);
        }
    }
    #pragma unroll
    for (int j = 0; j < 4; ++j) {
        float s = 0.0f, q = 0.0f;
        #pragma unroll
        for (int i = 0; i < 2; ++i)
            #pragma unroll
            for (int r = 0; r < 4; ++r) {
                float v = acc[i][j][r];
                s += v; q += v*v;
            }
        atomicAdd(&ls[colb + j*16], s);
        atomicAdd(&lq[colb + j*16], q);
    }
    __syncthreads();
    if (tid < CH) {
        atomicAdd(&gsum[tid], ls[tid]);
        atomicAdd(&gsq[tid],  lq[tid]);
    }
}

// ---------------------------------------------------------------------------
// norm_relu: xo(bf16) = relu(bn(y; g,b)),  y bf16, 8 elems/thread
// ---------------------------------------------------------------------------
__global__ __launch_bounds__(256)
void norm_relu_kernel(const u16* __restrict__ y, const float* __restrict__ sums,
                      const float* __restrict__ sumsq, const float* __restrict__ gam,
                      const float* __restrict__ bet, u16* __restrict__ xo)
{
    __shared__ float sc[128], sh[128];
    const int tid = threadIdx.x;
    if (tid < 128) {
        float mu  = sums[tid] * (1.0f/NPTS);
        float var = fmaxf(sumsq[tid] * (1.0f/NPTS) - mu*mu, 0.0f);
        float rs  = rsqrtf(var + 1e-5f);
        float s   = rs * gam[tid];
        sc[tid] = s; sh[tid] = bet[tid] - mu*s;
    }
    __syncthreads();
    size_t e = ((size_t)blockIdx.x*256 + tid) * 8;
    int c0 = (int)(e & 127);
    ushort4 lo = *(const ushort4*)(y + e);
    ushort4 hi = *(const ushort4*)(y + e + 4);
    ushort4 o0, o1;
    o0.x = f2bf(fmaxf(bf2f(lo.x)*sc[c0+0] + sh[c0+0], 0.0f));
    o0.y = f2bf(fmaxf(bf2f(lo.y)*sc[c0+1] + sh[c0+1], 0.0f));
    o0.z = f2bf(fmaxf(bf2f(lo.z)*sc[c0+2] + sh[c0+2], 0.0f));
    o0.w = f2bf(fmaxf(bf2f(lo.w)*sc[c0+3] + sh[c0+3], 0.0f));
    o1.x = f2bf(fmaxf(bf2f(hi.x)*sc[c0+4] + sh[c0+4], 0.0f));
    o1.y = f2bf(fmaxf(bf2f(hi.y)*sc[c0+5] + sh[c0+5], 0.0f));
    o1.z = f2bf(fmaxf(bf2f(hi.z)*sc[c0+6] + sh[c0+6], 0.0f));
    o1.w = f2bf(fmaxf(bf2f(hi.w)*sc[c0+7] + sh[c0+7], 0.0f));
    *(ushort4*)(xo + e) = o0;
    *(ushort4*)(xo + e + 4) = o1;
}

// ---------------------------------------------------------------------------
// final: out = relu(bn(y2; g,b) + feats)   (y2 bf16, feats/out fp32)
// ---------------------------------------------------------------------------
__global__ __launch_bounds__(256)
void final_kernel(const u16* __restrict__ y, const float* __restrict__ sums,
                  const float* __restrict__ sumsq, const float* __restrict__ gam,
                  const float* __restrict__ bet, const float* __restrict__ feats,
                  float* __restrict__ out)
{
    __shared__ float sc[128], sh[128];
    const int tid = threadIdx.x;
    if (tid < 128) {
        float mu  = sums[tid] * (1.0f/NPTS);
        float var = fmaxf(sumsq[tid] * (1.0f/NPTS) - mu*mu, 0.0f);
        float rs  = rsqrtf(var + 1e-5f);
        float s   = rs * gam[tid];
        sc[tid] = s; sh[tid] = bet[tid] - mu*s;
    }
    __syncthreads();
    size_t e = ((size_t)blockIdx.x*256 + tid) * 4;
    int c0 = (int)(e & 127);
    ushort4 in = *(const ushort4*)(y + e);
    float4 ft = *(const float4*)(feats + e);
    float4 o;
    o.x = fmaxf(bf2f(in.x)*sc[c0+0] + sh[c0+0] + ft.x, 0.0f);
    o.y = fmaxf(bf2f(in.y)*sc[c0+1] + sh[c0+1] + ft.y, 0.0f);
    o.z = fmaxf(bf2f(in.z)*sc[c0+2] + sh[c0+2] + ft.z, 0.0f);
    o.w = fmaxf(bf2f(in.w)*sc[c0+3] + sh[c0+3] + ft.w, 0.0f);
    *(float4*)(out + e) = o;
}

// ---------------------------------------------------------------------------
extern "C" void kernel_launch(void* const* d_in, const int* in_sizes, int n_in,
                              void* d_out, int out_size, void* d_ws, size_t ws_size,
                              hipStream_t stream)
{
    const float* feats = (const float*)d_in[0];
    const int*   nbr   = (const int*)d_in[1];
    const float* W1    = (const float*)d_in[2];
    const float* g1    = (const float*)d_in[3];
    const float* b1    = (const float*)d_in[4];
    const float* W2    = (const float*)d_in[5];
    const float* g2    = (const float*)d_in[6];
    const float* b2    = (const float*)d_in[7];
    float* out = (float*)d_out;

    // ws (~19 MB): xbuf bf16 | ybuf bf16 | Wt1 | Wt2 | stat[512]
    char* ws = (char*)d_ws;
    u16*   xbuf = (u16*)ws;                                   // 8.4 MB
    u16*   ybuf = xbuf + (size_t)NC;                          // 8.4 MB
    u16*   W1t  = ybuf + (size_t)NC;
    u16*   W2t  = W1t + (size_t)KOFF*CH*CH;
    float* stat = (float*)(W2t + (size_t)KOFF*CH*CH);         // s1,q1,s2,q2

    prep_kernel<<<dim3(2*KOFF + NC/2048), 256, 0, stream>>>(W1, W2, W1t, W2t, feats, xbuf, stat);

    ResidualBlock_77498389889548_kernel<<<dim3(NPTS/TILE_M), 256, 0, stream>>>(
        xbuf, nbr, W1t, ybuf, stat, stat + 128);
    norm_relu_kernel<<<dim3(NC/2048), 256, 0, stream>>>(ybuf, stat, stat + 128, g1, b1, xbuf);

    ResidualBlock_77498389889548_kernel<<<dim3(NPTS/TILE_M), 256, 0, stream>>>(
        xbuf, nbr, W2t, ybuf, stat + 256, stat + 384);
    final_kernel<<<dim3(NC/1024), 256, 0, stream>>>(ybuf, stat + 256, stat + 384, g2, b2, feats, out);
}